// Round 7
// baseline (3510.355 us; speedup 1.0000x reference)
//
#include <hip/hip_runtime.h>

#ifndef M_PI
#define M_PI 3.14159265358979323846
#endif

#define T_DATA 20000
#define E_NO_C 2000
#define I_NO_C 500
#define SUB 16
#define TNO 200
#define NGRP 2500   // groups of 8 steps

typedef float v2f __attribute__((ext_vector_type(2)));

// ---------------- Kernel A: filter kernels (e, i, spk, hist) -> d_out[320000..] ----------------
__global__ void filters_k(const float* __restrict__ Tau_e, const float* __restrict__ Tau_i,
                          const float* __restrict__ W_e,  const float* __restrict__ W_i,
                          const float* __restrict__ D_e,  const float* __restrict__ D_i,
                          const float* __restrict__ Tau_spk, const float* __restrict__ W_spk,
                          const float* __restrict__ W_hist,
                          float* __restrict__ filt_out) {
  int id = blockIdx.x * blockDim.x + threadIdx.x;
  if (id >= 64 * TNO) return;
  int r = id / TNO, x = id % TNO;
  int s = r & 15, kind = r >> 4;
  double xd = (double)x;
  double val;
  if (kind == 0) {
    double te = xd - exp((double)D_e[s]); te = te > 0.0 ? te : 0.0;
    double tt = te / exp((double)Tau_e[s]);
    val = tt * exp(-tt) * exp((double)W_e[s]);
  } else if (kind == 1) {
    double ti = xd - exp((double)D_i[s]); ti = ti > 0.0 ? ti : 0.0;
    double tt = ti / exp((double)Tau_i[s]);
    val = -tt * exp(-tt) * exp((double)W_i[s]);
  } else if (kind == 2) {
    double tt = xd / exp((double)Tau_spk[s]);
    val = tt * exp(-tt) * exp((double)W_spk[s]);
  } else {
    double raw = 4.0 * log(xd + 1.0);
    double acc = 0.0;
    for (int i = 0; i < 16; ++i) {
      double phi = (M_PI / 2.0) * (double)i;
      double b = (raw < phi - M_PI || raw > phi + M_PI) ? 0.0
                                                        : (0.5 * cos(raw - phi) + 0.5);
      acc += (double)W_hist[s * 16 + i] * b;
    }
    val = acc;
  }
  filt_out[id] = (float)val;
}

// ---------------- Kernel B: syn = S @ C^T, C staged in LDS tiles ----------------
#define ETILE 500
__global__ __launch_bounds__(256) void synmm_k(const float* __restrict__ S,
                                               const float* __restrict__ C,
                                               float* __restrict__ out, int E) {
  __shared__ __align__(16) float Cs[16][ETILE];
  int tid = threadIdx.x;
  int s = tid & 15, tt = tid >> 4;
  long t = (long)blockIdx.x * 16 + tt;
  const float* Srow = S + t * E;
  float acc = 0.f;
  for (int tb = 0; tb < E; tb += ETILE) {
    __syncthreads();
    for (int i = tid; i < 16 * ETILE; i += 256) {
      int s2 = i / ETILE, k2 = i - s2 * ETILE;
      Cs[s2][k2] = C[(long)s2 * E + tb + k2];
    }
    __syncthreads();
    const float* Crow = &Cs[s][0];
    const float* Sp = Srow + tb;
#pragma unroll 2
    for (int e = 0; e < ETILE; e += 4) {
      float4 a = *(const float4*)(Sp + e);
      float4 c = *(const float4*)(Crow + e);
      acc = fmaf(a.x, c.x, acc); acc = fmaf(a.y, c.y, acc);
      acc = fmaf(a.z, c.z, acc); acc = fmaf(a.w, c.w, acc);
    }
  }
  out[t * 16 + s] = acc;
}

// ---------------- Kernel C: causal depthwise conv + Theta, TRANSPOSED output ----------------
__global__ void conv_k(const float* __restrict__ syn_e, const float* __restrict__ syn_i,
                       const float* __restrict__ filt, const float* __restrict__ Theta,
                       float* __restrict__ synT) {
  __shared__ float ek[16][201];
  __shared__ float ik[16][201];
  int tid = threadIdx.x;
  for (int idx = tid; idx < 16 * TNO; idx += 256) {
    ek[idx / TNO][idx % TNO] = filt[idx];
    ik[idx / TNO][idx % TNO] = filt[16 * TNO + idx];
  }
  __syncthreads();
  int s = tid & 15, tt = tid >> 4;
  int t = blockIdx.x * 16 + tt;
  float acc = Theta[s];
  if (t >= TNO) {
#pragma unroll 4
    for (int j = 0; j < TNO; ++j) {
      int u = t - 1 - j;
      acc += ek[s][j] * syn_e[u * 16 + s] + ik[s][j] * syn_i[u * 16 + s];
    }
  } else {
    for (int j = 0; j < t; ++j) {
      int u = t - 1 - j;
      acc += ek[s][j] * syn_e[u * 16 + s] + ik[s][j] * syn_i[u * 16 + s];
    }
  }
  synT[(long)s * T_DATA + t] = acc;
}

// ---------------- Kernel D: barrier-free producer/consumer scan (LDS seqlock) ----------------
// No s_barrier in the loop -> no vmcnt(0) drains; only lgkmcnt(0) before seq publishes.
// Wave 0 (scan): 8 steps/iter; mid dots (delays K+1..K+8 from prev regs), pend scatter
//   (in-group delays 2..7), delay-1 on the chain, popcount-fp64-IIR mix (2-step slack).
// Waves 1-3 (gather): o for group I+1, delays >= K+9 (window ends time 8I-1, gated by
//   seqS >= I); full 2-level shuffle; 1 partial/wave. Wave 1 stores spk_out (group I-1).
__global__ __launch_bounds__(256, 1) void scan6_k(const float* __restrict__ synT,
                                                  const float* __restrict__ filt,
                                                  const float* __restrict__ C_den,
                                                  const float* __restrict__ Tau_spk,
                                                  const float* __restrict__ W_spk,
                                                  float* __restrict__ spk_out) {
  __shared__ __align__(16) float ring[16][452];      // [s][pos], mirror pos+256 for pos<192
  __shared__ __align__(16) float oPart[2][3][16][8]; // [slot][w][s][K]
  __shared__ int seqS_s;
  __shared__ int gseq_s[3];
  const int tid = threadIdx.x;
  const int widx = tid >> 6;
  const int l = tid & 63;
  const int s = l & 15, q = l >> 4;

  for (int i = tid; i < 16 * 452; i += 256) (&ring[0][0])[i] = 0.f;
  for (int i = tid; i < 2 * 3 * 16 * 8; i += 256) (&oPart[0][0][0][0])[i] = 0.f;
  if (tid == 0) { seqS_s = 0; gseq_s[0] = 0; gseq_s[1] = 0; gseq_s[2] = 0; }
  __syncthreads();   // once, outside the loop

  volatile int* vS = &seqS_s;
  volatile int* vG = &gseq_s[0];

  if (widx == 0) {
    // ================= scan wave =================
    const float* hrow = filt + (48 + s) * TNO;
    float hk[15];
#pragma unroll
    for (int i = 0; i < 15; ++i) hk[i] = hrow[i];

    float t0v = Tau_spk[0], w0v = W_spk[0];
    bool okrow = (Tau_spk[s] == t0v) && (W_spk[s] == w0v);
    unsigned cd = 0u;
#pragma unroll
    for (int j = 0; j < 16; ++j) {
      float cv = C_den[s * 16 + j];
      okrow = okrow && (cv == 0.f || cv == 1.f);
      cd |= (cv != 0.f) ? (1u << j) : 0u;
    }
    const bool uni = (bool)__all((int)okrow);

    const double tau  = exp((double)Tau_spk[s]);
    const double aa   = exp(-1.0 / tau);
    const double c2a  = exp((double)W_spk[s]) * aa / tau;  // K[d]=C(d-1)a^(d-1), C=w/tau
    const double twoa = 2.0 * aa;
    const double na2  = -aa * aa;

    double twoa4[4], na24[4], c2a4[4], yd0a[4], yd1a[4];
    float cden4[4];
#pragma unroll
    for (int r = 0; r < 4; ++r) {
      int j = 4 * q + r;
      double tj = exp((double)Tau_spk[j]);
      double aj = exp(-1.0 / tj);
      twoa4[r] = 2.0 * aj; na24[r] = -aj * aj;
      c2a4[r]  = exp((double)W_spk[j]) * aj / tj;
      yd0a[r] = 0.0; yd1a[r] = 0.0;
      cden4[r] = C_den[s * 16 + j];
    }

    double zA = 0.0, zB = 0.0;
    float mixu = 0.f, mix1 = 0.f;
    float prev[8];
#pragma unroll
    for (int i = 0; i < 8; ++i) prev[i] = 0.f;

    // 2-deep synT register pipeline: groups I, I+1
    float4 svA0 = *(const float4*)(synT + (long)s * T_DATA + 0);
    float4 svB0 = *(const float4*)(synT + (long)s * T_DATA + 4);
    float4 svA1 = *(const float4*)(synT + (long)s * T_DATA + 8);
    float4 svB1 = *(const float4*)(synT + (long)s * T_DATA + 12);

#define STEP(K, D1)                                                           \
    {                                                                         \
      float pre = base[K] + (pend[K] + mixu);                                 \
      float sub = fmaf(hk[0], (D1), pre);                                     \
      unsigned long long bal = __ballot(sub > 0.f);                           \
      float sg = sub > 0.f ? 1.f : 0.f;                                       \
      unsigned mk = (unsigned)bal & 0xFFFFu;                                  \
      if (uni) {                                                              \
        double zc = fma(twoa, zB, fma(na2, zA, c2a * (double)__popc(mk & cd))); \
        zA = zB; zB = zc;                                                     \
        mixu = (float)zA;                                                     \
      } else {                                                                \
        float p = 0.f;                                                        \
        _Pragma("unroll")                                                     \
        for (int r = 0; r < 4; ++r) {                                         \
          double xr = (double)((mk >> (4 * q + r)) & 1u);                     \
          double y2 = fma(twoa4[r], yd1a[r], fma(na24[r], yd0a[r], c2a4[r] * xr)); \
          yd0a[r] = yd1a[r]; yd1a[r] = y2;                                    \
          p = fmaf(cden4[r], (float)y2, p);                                   \
        }                                                                     \
        p += __shfl_xor(p, 16); p += __shfl_xor(p, 32);                       \
        float mixn = mix1; mix1 = p;                                          \
        mixu = mixn;                                                          \
      }                                                                       \
      _Pragma("unroll")                                                       \
      for (int dd = 2; dd < 8; ++dd)                                          \
        if ((K) + dd < 8) pend[(K) + dd] = fmaf(hk[dd - 1], sg, pend[(K) + dd]); \
      S[(K)] = sg;                                                            \
    }

    for (int I = 0; I < NGRP; ++I) {
      // issue global load for group I+2 early (no barrier will drain it)
      float4 svA2, svB2;
      if (I + 2 < NGRP) {
        svA2 = *(const float4*)(synT + (long)s * T_DATA + 8 * (I + 2));
        svB2 = *(const float4*)(synT + (long)s * T_DATA + 8 * (I + 2) + 4);
      } else {
        svA2.x = svA2.y = svA2.z = svA2.w = 0.f;
        svB2.x = svB2.y = svB2.z = svB2.w = 0.f;
      }

      // wait for o[group I] (written by gather iter I-1); trivially true at I=0
      while (vG[0] < I) {}
      while (vG[1] < I) {}
      while (vG[2] < I) {}
      asm volatile("" ::: "memory");

      const int sl = I & 1;
      float4 g0a = *(const float4*)&oPart[sl][0][s][0];
      float4 g0b = *(const float4*)&oPart[sl][0][s][4];
      float4 g1a = *(const float4*)&oPart[sl][1][s][0];
      float4 g1b = *(const float4*)&oPart[sl][1][s][4];
      float4 g2a = *(const float4*)&oPart[sl][2][s][0];
      float4 g2b = *(const float4*)&oPart[sl][2][s][4];

      // mid dots: delays K+1..K+8 from prev[] (K=0 skips d=0 -> delay-1 on chain)
      float mid[8];
#pragma unroll
      for (int K = 0; K < 8; ++K) {
        float m = 0.f;
#pragma unroll
        for (int d = 0; d < 8; ++d) {
          if (K == 0 && d == 0) continue;
          m = fmaf(hk[K + d], prev[d], m);
        }
        mid[K] = m;
      }

      float4 ocA, ocB;
      ocA.x = (g0a.x + g1a.x) + g2a.x; ocA.y = (g0a.y + g1a.y) + g2a.y;
      ocA.z = (g0a.z + g1a.z) + g2a.z; ocA.w = (g0a.w + g1a.w) + g2a.w;
      ocB.x = (g0b.x + g1b.x) + g2b.x; ocB.y = (g0b.y + g1b.y) + g2b.y;
      ocB.z = (g0b.z + g1b.z) + g2b.z; ocB.w = (g0b.w + g1b.w) + g2b.w;

      float base[8];
      base[0] = (mid[0] + ocA.x) + svA0.x;
      base[1] = (mid[1] + ocA.y) + svA0.y;
      base[2] = (mid[2] + ocA.z) + svA0.z;
      base[3] = (mid[3] + ocA.w) + svA0.w;
      base[4] = (mid[4] + ocB.x) + svB0.x;
      base[5] = (mid[5] + ocB.y) + svB0.y;
      base[6] = (mid[6] + ocB.z) + svB0.z;
      base[7] = (mid[7] + ocB.w) + svB0.w;

      float pend[8];
#pragma unroll
      for (int i = 0; i < 8; ++i) pend[i] = 0.f;
      float S[8];

      STEP(0, prev[0])
      STEP(1, S[0])
      STEP(2, S[1])
      STEP(3, S[2])
      STEP(4, S[3])
      STEP(5, S[4])
      STEP(6, S[5])
      STEP(7, S[6])

      if (l < 16) {
        int u = (8 * I) & 255;
        float4 w0; w0.x = S[0]; w0.y = S[1]; w0.z = S[2]; w0.w = S[3];
        float4 w1; w1.x = S[4]; w1.y = S[5]; w1.z = S[6]; w1.w = S[7];
        *(float4*)&ring[s][u] = w0;
        *(float4*)&ring[s][u + 4] = w1;
        if (u <= 184) {
          *(float4*)&ring[s][u + 256] = w0;
          *(float4*)&ring[s][u + 260] = w1;
        }
      }
      asm volatile("s_waitcnt lgkmcnt(0)" ::: "memory");
      if (l == 0) *vS = I + 1;

#pragma unroll
      for (int d = 0; d < 8; ++d) prev[d] = S[7 - d];
      svA0 = svA1; svB0 = svB1; svA1 = svA2; svB1 = svB2;
    }
#undef STEP
  } else {
    // ================= gather waves (w = 0..2): o for group I+1, delays >= K+9 =================
    const int w = widx - 1;
    const int g = w * 4 + q;                 // lane-group 0..11, 16 window positions each
    const float* hrow = filt + (48 + s) * TNO;
    float ca[23];
#pragma unroll
    for (int n = 0; n < 23; ++n) {
      int idx = 184 - 16 * g + n;
      ca[n] = (idx <= 199) ? hrow[idx] : 0.f;
    }
    v2f pr[23];
    pr[0].x = 0.f; pr[0].y = 0.f;
#pragma unroll
    for (int m = 1; m < 23; ++m) { pr[m].x = ca[m]; pr[m].y = ca[m - 1]; }

    for (int I = 0; I < NGRP; ++I) {
      // need spikes through time 8I-1 (scan groups <= I-1): seqS >= I
      while (*vS < I) {}
      asm volatile("" ::: "memory");

      int Pe = (8 * I - 1) & 255;
      if (Pe < 191) Pe += 256;
      const float4* rp = (const float4*)&ring[s][(Pe - 191) + 16 * g];
      float4 V0 = rp[0], V1 = rp[1], V2 = rp[2], V3 = rp[3];

      v2f aE[8], aO[8];
#pragma unroll
      for (int K = 0; K < 8; ++K) {
        aE[K].x = 0.f; aE[K].y = 0.f; aO[K].x = 0.f; aO[K].y = 0.f;
      }
#define GMAC(V, J, ACC)                                   \
      { v2f A;  A.x  = (V).x; A.y  = (V).y;               \
        v2f Bv; Bv.x = (V).z; Bv.y = (V).w;               \
        _Pragma("unroll")                                 \
        for (int K = 0; K < 8; ++K) {                     \
          ACC[K] += pr[15 + K - 4 * (J)] * A;             \
          ACC[K] += pr[13 + K - 4 * (J)] * Bv;            \
        } }
      GMAC(V0, 0, aE) GMAC(V1, 1, aO) GMAC(V2, 2, aE) GMAC(V3, 3, aO)
#undef GMAC
      float o[8];
#pragma unroll
      for (int K = 0; K < 8; ++K) {
        v2f t = aE[K] + aO[K];
        float v = t.x + t.y;
        v += __shfl_xor(v, 16);
        v += __shfl_xor(v, 32);
        o[K] = v;
      }
      if (l < 16) {
        float4 pa; pa.x = o[0]; pa.y = o[1]; pa.z = o[2]; pa.w = o[3];
        float4 pb; pb.x = o[4]; pb.y = o[5]; pb.z = o[6]; pb.w = o[7];
        *(float4*)&oPart[(I + 1) & 1][w][s][0] = pa;
        *(float4*)&oPart[(I + 1) & 1][w][s][4] = pb;
      }
      asm volatile("s_waitcnt lgkmcnt(0)" ::: "memory");
      if (l == 0) vG[w] = I + 1;

      if (w == 1 && I > 0) {
        // spikes of group I-1 (gated by seqS >= I above); coalesced 128-float store
        int u = (8 * (I - 1)) & 255;
        spk_out[(long)(I - 1) * 128 + l]      = ring[s][u + q];
        spk_out[(long)(I - 1) * 128 + 64 + l] = ring[s][u + 4 + q];
      }
    }
    if (w == 1) {
      while (*vS < NGRP) {}
      asm volatile("" ::: "memory");
      int u = (8 * (NGRP - 1)) & 255;
      spk_out[(long)(NGRP - 1) * 128 + l]      = ring[s][u + q];
      spk_out[(long)(NGRP - 1) * 128 + 64 + l] = ring[s][u + 4 + q];
    }
  }
}

extern "C" void kernel_launch(void* const* d_in, const int* in_sizes, int n_in,
                              void* d_out, int out_size, void* d_ws, size_t ws_size,
                              hipStream_t stream) {
  const float* S_e     = (const float*)d_in[0];
  const float* S_i     = (const float*)d_in[1];
  const float* C_den   = (const float*)d_in[2];
  const float* C_syn_e = (const float*)d_in[3];
  const float* C_syn_i = (const float*)d_in[4];
  const float* Tau_e   = (const float*)d_in[5];
  const float* Tau_i   = (const float*)d_in[6];
  const float* W_e     = (const float*)d_in[7];
  const float* W_i     = (const float*)d_in[8];
  const float* D_e     = (const float*)d_in[9];
  const float* D_i     = (const float*)d_in[10];
  const float* Tau_spk = (const float*)d_in[11];
  const float* W_spk   = (const float*)d_in[12];
  const float* W_hist  = (const float*)d_in[13];
  const float* Theta   = (const float*)d_in[14];

  float* out     = (float*)d_out;
  float* spk_out = out;            // 20000*16
  float* filt    = out + 320000;   // 64*200

  float* ws    = (float*)d_ws;
  float* syn_e = ws;               // 320000
  float* syn_i = ws + 320000;      // 320000
  float* synT  = ws + 640000;      // 320000 (transposed [s][t])

  filters_k<<<50, 256, 0, stream>>>(Tau_e, Tau_i, W_e, W_i, D_e, D_i,
                                    Tau_spk, W_spk, W_hist, filt);
  synmm_k<<<1250, 256, 0, stream>>>(S_e, C_syn_e, syn_e, E_NO_C);
  synmm_k<<<1250, 256, 0, stream>>>(S_i, C_syn_i, syn_i, I_NO_C);
  conv_k<<<1250, 256, 0, stream>>>(syn_e, syn_i, filt, Theta, synT);
  scan6_k<<<1, 256, 0, stream>>>(synT, filt, C_den, Tau_spk, W_spk, spk_out);
}

// Round 8
// 3357.814 us; speedup vs baseline: 1.0454x; 1.0454x over previous
//
#include <hip/hip_runtime.h>

#ifndef M_PI
#define M_PI 3.14159265358979323846
#endif

#define T_DATA 20000
#define E_NO_C 2000
#define I_NO_C 500
#define SUB 16
#define TNO 200
#define NGRP 5000   // 4-step groups

typedef float v2f __attribute__((ext_vector_type(2)));

// ---------------- Kernel A: filter kernels (e, i, spk, hist) -> d_out[320000..] ----------------
__global__ void filters_k(const float* __restrict__ Tau_e, const float* __restrict__ Tau_i,
                          const float* __restrict__ W_e,  const float* __restrict__ W_i,
                          const float* __restrict__ D_e,  const float* __restrict__ D_i,
                          const float* __restrict__ Tau_spk, const float* __restrict__ W_spk,
                          const float* __restrict__ W_hist,
                          float* __restrict__ filt_out) {
  int id = blockIdx.x * blockDim.x + threadIdx.x;
  if (id >= 64 * TNO) return;
  int r = id / TNO, x = id % TNO;
  int s = r & 15, kind = r >> 4;
  double xd = (double)x;
  double val;
  if (kind == 0) {
    double te = xd - exp((double)D_e[s]); te = te > 0.0 ? te : 0.0;
    double tt = te / exp((double)Tau_e[s]);
    val = tt * exp(-tt) * exp((double)W_e[s]);
  } else if (kind == 1) {
    double ti = xd - exp((double)D_i[s]); ti = ti > 0.0 ? ti : 0.0;
    double tt = ti / exp((double)Tau_i[s]);
    val = -tt * exp(-tt) * exp((double)W_i[s]);
  } else if (kind == 2) {
    double tt = xd / exp((double)Tau_spk[s]);
    val = tt * exp(-tt) * exp((double)W_spk[s]);
  } else {
    double raw = 4.0 * log(xd + 1.0);
    double acc = 0.0;
    for (int i = 0; i < 16; ++i) {
      double phi = (M_PI / 2.0) * (double)i;
      double b = (raw < phi - M_PI || raw > phi + M_PI) ? 0.0
                                                        : (0.5 * cos(raw - phi) + 0.5);
      acc += (double)W_hist[s * 16 + i] * b;
    }
    val = acc;
  }
  filt_out[id] = (float)val;
}

// ---------------- Kernel B: syn = S @ C^T, C staged in LDS tiles ----------------
#define ETILE 500
__global__ __launch_bounds__(256) void synmm_k(const float* __restrict__ S,
                                               const float* __restrict__ C,
                                               float* __restrict__ out, int E) {
  __shared__ __align__(16) float Cs[16][ETILE];
  int tid = threadIdx.x;
  int s = tid & 15, tt = tid >> 4;
  long t = (long)blockIdx.x * 16 + tt;
  const float* Srow = S + t * E;
  float acc = 0.f;
  for (int tb = 0; tb < E; tb += ETILE) {
    __syncthreads();
    for (int i = tid; i < 16 * ETILE; i += 256) {
      int s2 = i / ETILE, k2 = i - s2 * ETILE;
      Cs[s2][k2] = C[(long)s2 * E + tb + k2];
    }
    __syncthreads();
    const float* Crow = &Cs[s][0];
    const float* Sp = Srow + tb;
#pragma unroll 2
    for (int e = 0; e < ETILE; e += 4) {
      float4 a = *(const float4*)(Sp + e);
      float4 c = *(const float4*)(Crow + e);
      acc = fmaf(a.x, c.x, acc); acc = fmaf(a.y, c.y, acc);
      acc = fmaf(a.z, c.z, acc); acc = fmaf(a.w, c.w, acc);
    }
  }
  out[t * 16 + s] = acc;
}

// ---------------- Kernel C: causal depthwise conv + Theta, [t][s] layout ----------------
__global__ void conv_k(const float* __restrict__ syn_e, const float* __restrict__ syn_i,
                       const float* __restrict__ filt, const float* __restrict__ Theta,
                       float* __restrict__ synTh) {
  __shared__ float ek[16][201];
  __shared__ float ik[16][201];
  int tid = threadIdx.x;
  for (int idx = tid; idx < 16 * TNO; idx += 256) {
    ek[idx / TNO][idx % TNO] = filt[idx];
    ik[idx / TNO][idx % TNO] = filt[16 * TNO + idx];
  }
  __syncthreads();
  int s = tid & 15, tt = tid >> 4;
  int t = blockIdx.x * 16 + tt;
  float acc = Theta[s];
  if (t >= TNO) {
#pragma unroll 4
    for (int j = 0; j < TNO; ++j) {
      int u = t - 1 - j;
      acc += ek[s][j] * syn_e[u * 16 + s] + ik[s][j] * syn_i[u * 16 + s];
    }
  } else {
    for (int j = 0; j < t; ++j) {
      int u = t - 1 - j;
      acc += ek[s][j] * syn_e[u * 16 + s] + ik[s][j] * syn_i[u * 16 + s];
    }
  }
  synTh[t * 16 + s] = acc;
}

// ---------------- Kernel D: R4 skeleton (barrier, lag-2, 4-step groups), surgical cuts ----------------
// scan wave: NO global memory ops (no vmcnt drain on its barrier). synTh comes from LDS
//   (staged by gather wave 2 in 16-group batches). oPart partials prefetched 1 iter early.
// gather waves: no shuffles — raw per-chunk float4 partial per lane; ~200 cyc/iter.
// wave 1: spk_out stores at iteration TOP (drain overlaps full iter of gather work).
__global__ __launch_bounds__(256, 1) void scan7_k(const float* __restrict__ synTh,
                                                  const float* __restrict__ filt,
                                                  const float* __restrict__ C_den,
                                                  const float* __restrict__ Tau_spk,
                                                  const float* __restrict__ W_spk,
                                                  float* __restrict__ spk_out) {
  __shared__ __align__(16) float ring[16][452];        // [s][pos], mirror pos+256 for pos<192
  __shared__ __align__(16) float oPart[3][3][4][16][4]; // [slot][w][q][s][K]
  __shared__ __align__(16) float synBuf[2][1024];       // 16 groups x 64 floats, double-buffered
  const int tid = threadIdx.x;
  const int widx = tid >> 6;
  const int l = tid & 63;
  const int s = l & 15, q = l >> 4;

  for (int i = tid; i < 16 * 452; i += 256) (&ring[0][0])[i] = 0.f;
  for (int i = tid; i < 3 * 3 * 4 * 16 * 4; i += 256) (&oPart[0][0][0][0][0])[i] = 0.f;
  if (widx == 3) {  // preload synTh groups 0..15
#pragma unroll
    for (int k = 0; k < 4; ++k) {
      float4 v = *(const float4*)&synTh[(k * 64 + l) * 4];
      *(float4*)&synBuf[0][(k * 64 + l) * 4] = v;
    }
  }
  __syncthreads();

  if (widx == 0) {
    // ================= scan wave =================
    const float* hrow = filt + (48 + s) * TNO;
    float hk[11];
#pragma unroll
    for (int i = 0; i < 11; ++i) hk[i] = hrow[i];

    float t0v = Tau_spk[0], w0v = W_spk[0];
    bool okrow = (Tau_spk[s] == t0v) && (W_spk[s] == w0v);
    unsigned cd = 0u;
#pragma unroll
    for (int j = 0; j < 16; ++j) {
      float cv = C_den[s * 16 + j];
      okrow = okrow && (cv == 0.f || cv == 1.f);
      cd |= (cv != 0.f) ? (1u << j) : 0u;
    }
    const bool uni = (bool)__all((int)okrow);

    const double tau  = exp((double)Tau_spk[s]);
    const double aa   = exp(-1.0 / tau);
    const double c2a  = exp((double)W_spk[s]) * aa / tau;  // K[d]=C(d-1)a^(d-1), C=w/tau
    const double twoa = 2.0 * aa;
    const double na2  = -aa * aa;

    double twoa4[4], na24[4], c2a4[4], yd0a[4], yd1a[4];
    float cden4[4];
#pragma unroll
    for (int r = 0; r < 4; ++r) {
      int j = 4 * q + r;
      double tj = exp((double)Tau_spk[j]);
      double aj = exp(-1.0 / tj);
      twoa4[r] = 2.0 * aj; na24[r] = -aj * aj;
      c2a4[r]  = exp((double)W_spk[j]) * aj / tj;
      yd0a[r] = 0.0; yd1a[r] = 0.0;
      cden4[r] = C_den[s * 16 + j];
    }

    double zA = 0.0, zB = 0.0;
    float mixu = 0.f, mix1 = 0.f;
    float prev[8];
#pragma unroll
    for (int i = 0; i < 8; ++i) prev[i] = 0.f;

    float oc[4] = {0.f, 0.f, 0.f, 0.f};    // group 0: all gather delays hit t<0 -> 0
    float synC[4];
#pragma unroll
    for (int K = 0; K < 4; ++K) synC[K] = synBuf[0][K * 16 + s];

#define STEP(K, D1)                                                           \
    {                                                                         \
      float pre = base[K] + (pend[K] + mixu);                                 \
      float sub = fmaf(hk[0], (D1), pre);                                     \
      unsigned long long bal = __ballot(sub > 0.f);                           \
      float sg = sub > 0.f ? 1.f : 0.f;                                       \
      unsigned mk = (unsigned)bal & 0xFFFFu;                                  \
      if (uni) {                                                              \
        double zc = fma(twoa, zB, fma(na2, zA, c2a * (double)__popc(mk & cd))); \
        zA = zB; zB = zc;                                                     \
        mixu = (float)zA;                                                     \
      } else {                                                                \
        float p = 0.f;                                                        \
        _Pragma("unroll")                                                     \
        for (int r = 0; r < 4; ++r) {                                         \
          double xr = (double)((mk >> (4 * q + r)) & 1u);                     \
          double y2 = fma(twoa4[r], yd1a[r], fma(na24[r], yd0a[r], c2a4[r] * xr)); \
          yd0a[r] = yd1a[r]; yd1a[r] = y2;                                    \
          p = fmaf(cden4[r], (float)y2, p);                                   \
        }                                                                     \
        p += __shfl_xor(p, 16); p += __shfl_xor(p, 32);                       \
        float mixn = mix1; mix1 = p;                                          \
        mixu = mixn;                                                          \
      }                                                                       \
      _Pragma("unroll")                                                       \
      for (int dd = 2; dd < 4; ++dd)                                          \
        if ((K) + dd < 4) pend[(K) + dd] = fmaf(hk[dd - 1], sg, pend[(K) + dd]); \
      S[(K)] = sg;                                                            \
    }

    for (int I = 0; I < NGRP; ++I) {
      // prefetch group I+1: oPart slot (written at iter I-1, settled) + synBuf
      const int slotN = (I + 1) % 3;
      float4 op[12];
#pragma unroll
      for (int w = 0; w < 3; ++w)
#pragma unroll
        for (int q2 = 0; q2 < 4; ++q2)
          op[w * 4 + q2] = *(const float4*)&oPart[slotN][w][q2][s][0];
      const int bufN = ((I + 1) >> 4) & 1, slN = (I + 1) & 15;
      float synN[4];
#pragma unroll
      for (int K = 0; K < 4; ++K) synN[K] = synBuf[bufN][slN * 64 + K * 16 + s];

      // mid: delays K+1..K+8 from prev[] (K=0 skips d=0 -> delay 1 on the chain)
      float mid[4];
#pragma unroll
      for (int K = 0; K < 4; ++K) {
        float m = 0.f;
#pragma unroll
        for (int d = 0; d < 8; ++d) {
          if (K == 0 && d == 0) continue;
          m = fmaf(hk[K + d], prev[d], m);
        }
        mid[K] = m;
      }
      float base[4];
#pragma unroll
      for (int K = 0; K < 4; ++K) base[K] = (mid[K] + oc[K]) + synC[K];

      float pend[4] = {0.f, 0.f, 0.f, 0.f};
      float S[4];
      STEP(0, prev[0])
      STEP(1, S[0])
      STEP(2, S[1])
      STEP(3, S[2])

      if (l < 16) {
        int u = (4 * I) & 255;
        float4 w0; w0.x = S[0]; w0.y = S[1]; w0.z = S[2]; w0.w = S[3];
        *(float4*)&ring[s][u] = w0;
        if (u < 192) *(float4*)&ring[s][u + 256] = w0;
      }

      // sum the 12 prefetched partials (data long arrived) -> oc for group I+1
#pragma unroll
      for (int K = 0; K < 4; ++K) {
        float a01 = (&op[0].x)[K] + (&op[1].x)[K];
        float a23 = (&op[2].x)[K] + (&op[3].x)[K];
        float a45 = (&op[4].x)[K] + (&op[5].x)[K];
        float a67 = (&op[6].x)[K] + (&op[7].x)[K];
        float a89 = (&op[8].x)[K] + (&op[9].x)[K];
        float aAB = (&op[10].x)[K] + (&op[11].x)[K];
        oc[K] = ((a01 + a23) + (a45 + a67)) + (a89 + aAB);
        synC[K] = synN[K];
      }

      prev[7] = prev[3]; prev[6] = prev[2]; prev[5] = prev[1]; prev[4] = prev[0];
      prev[3] = S[0]; prev[2] = S[1]; prev[1] = S[2]; prev[0] = S[3];
      __syncthreads();
    }
#undef STEP
  } else {
    // ================= gather waves (w=0..2): group I+2, delays >= K+9, no shuffles =========
    const int w = widx - 1;
    const int g = w * 4 + q;                 // chunk 0..11, 16 window positions each
    const float* hrow = filt + (48 + s) * TNO;
    float ca[23];
#pragma unroll
    for (int n = 0; n < 23; ++n) {
      int idx = 184 - 16 * g + n;
      ca[n] = (idx <= 199) ? hrow[idx] : 0.f;
    }
    v2f pr[23];
    pr[0].x = 0.f; pr[0].y = 0.f;
#pragma unroll
    for (int m = 1; m < 23; ++m) { pr[m].x = ca[m]; pr[m].y = ca[m - 1]; }

    for (int I = 0; I < NGRP; ++I) {
      // wave 1: store group I-1's spikes FIRST (drain overlaps this iter's work)
      if (w == 1 && I > 0) {
        int u = (4 * (I - 1)) & 255;
        spk_out[(long)64 * (I - 1) + l] = ring[s][u + q];
      }
      // wave 2: stage 16 future synTh groups once per 16 iters (drain amortized)
      if (w == 2 && (I & 15) == 0) {
        int buf = ((I >> 4) + 1) & 1;
        int fbase = 64 * (I + 16);
#pragma unroll
        for (int k = 0; k < 4; ++k) {
          int fi = fbase + (k * 64 + l) * 4;
          float4 v;
          if (fi + 3 < 64 * NGRP) v = *(const float4*)&synTh[fi];
          else { v.x = 0.f; v.y = 0.f; v.z = 0.f; v.w = 0.f; }
          *(float4*)&synBuf[buf][(k * 64 + l) * 4] = v;
        }
      }

      int Pe = (4 * I - 1) & 255;
      if (Pe < 191) Pe += 256;
      const float4* rp = (const float4*)&ring[s][(Pe - 191) + 16 * g];
      float4 V0 = rp[0], V1 = rp[1], V2 = rp[2], V3 = rp[3];

      v2f a0 = {0.f, 0.f}, a1 = {0.f, 0.f}, a2 = {0.f, 0.f}, a3 = {0.f, 0.f};
#define MAC4(V, J)                                                     \
      {                                                                \
        v2f A; A.x = (V).x; A.y = (V).y;                               \
        v2f B; B.x = (V).z; B.y = (V).w;                               \
        a0 += pr[15 - 4 * (J)] * A; a0 += pr[13 - 4 * (J)] * B;        \
        a1 += pr[16 - 4 * (J)] * A; a1 += pr[14 - 4 * (J)] * B;        \
        a2 += pr[17 - 4 * (J)] * A; a2 += pr[15 - 4 * (J)] * B;        \
        a3 += pr[18 - 4 * (J)] * A; a3 += pr[16 - 4 * (J)] * B;        \
      }
      MAC4(V0, 0) MAC4(V1, 1) MAC4(V2, 2) MAC4(V3, 3)
#undef MAC4
      float4 ov;
      ov.x = a0.x + a0.y; ov.y = a1.x + a1.y;
      ov.z = a2.x + a2.y; ov.w = a3.x + a3.y;
      *(float4*)&oPart[(I + 2) % 3][w][q][s][0] = ov;
      __syncthreads();
    }
    if (w == 1) {  // tail: last group's spikes (final barrier already passed)
      int u = (4 * (NGRP - 1)) & 255;
      spk_out[(long)64 * (NGRP - 1) + l] = ring[s][u + q];
    }
  }
}

extern "C" void kernel_launch(void* const* d_in, const int* in_sizes, int n_in,
                              void* d_out, int out_size, void* d_ws, size_t ws_size,
                              hipStream_t stream) {
  const float* S_e     = (const float*)d_in[0];
  const float* S_i     = (const float*)d_in[1];
  const float* C_den   = (const float*)d_in[2];
  const float* C_syn_e = (const float*)d_in[3];
  const float* C_syn_i = (const float*)d_in[4];
  const float* Tau_e   = (const float*)d_in[5];
  const float* Tau_i   = (const float*)d_in[6];
  const float* W_e     = (const float*)d_in[7];
  const float* W_i     = (const float*)d_in[8];
  const float* D_e     = (const float*)d_in[9];
  const float* D_i     = (const float*)d_in[10];
  const float* Tau_spk = (const float*)d_in[11];
  const float* W_spk   = (const float*)d_in[12];
  const float* W_hist  = (const float*)d_in[13];
  const float* Theta   = (const float*)d_in[14];

  float* out     = (float*)d_out;
  float* spk_out = out;            // 20000*16
  float* filt    = out + 320000;   // 64*200

  float* ws    = (float*)d_ws;
  float* syn_e = ws;               // 320000
  float* syn_i = ws + 320000;      // 320000
  float* synTh = ws + 640000;      // 320000  ([t][s] layout)

  filters_k<<<50, 256, 0, stream>>>(Tau_e, Tau_i, W_e, W_i, D_e, D_i,
                                    Tau_spk, W_spk, W_hist, filt);
  synmm_k<<<1250, 256, 0, stream>>>(S_e, C_syn_e, syn_e, E_NO_C);
  synmm_k<<<1250, 256, 0, stream>>>(S_i, C_syn_i, syn_i, I_NO_C);
  conv_k<<<1250, 256, 0, stream>>>(syn_e, syn_i, filt, Theta, synTh);
  scan7_k<<<1, 256, 0, stream>>>(synTh, filt, C_den, Tau_spk, W_spk, spk_out);
}

// Round 9
// 2633.783 us; speedup vs baseline: 1.3328x; 1.2749x over previous
//
#include <hip/hip_runtime.h>

#ifndef M_PI
#define M_PI 3.14159265358979323846
#endif

#define T_DATA 20000
#define E_NO_C 2000
#define I_NO_C 500
#define SUB 16
#define TNO 200
#define NGRP 5000   // 4-step groups

typedef float v2f __attribute__((ext_vector_type(2)));

// ---------------- Kernel A: filter kernels (e, i, spk, hist) -> d_out[320000..] ----------------
__global__ void filters_k(const float* __restrict__ Tau_e, const float* __restrict__ Tau_i,
                          const float* __restrict__ W_e,  const float* __restrict__ W_i,
                          const float* __restrict__ D_e,  const float* __restrict__ D_i,
                          const float* __restrict__ Tau_spk, const float* __restrict__ W_spk,
                          const float* __restrict__ W_hist,
                          float* __restrict__ filt_out) {
  int id = blockIdx.x * blockDim.x + threadIdx.x;
  if (id >= 64 * TNO) return;
  int r = id / TNO, x = id % TNO;
  int s = r & 15, kind = r >> 4;
  double xd = (double)x;
  double val;
  if (kind == 0) {
    double te = xd - exp((double)D_e[s]); te = te > 0.0 ? te : 0.0;
    double tt = te / exp((double)Tau_e[s]);
    val = tt * exp(-tt) * exp((double)W_e[s]);
  } else if (kind == 1) {
    double ti = xd - exp((double)D_i[s]); ti = ti > 0.0 ? ti : 0.0;
    double tt = ti / exp((double)Tau_i[s]);
    val = -tt * exp(-tt) * exp((double)W_i[s]);
  } else if (kind == 2) {
    double tt = xd / exp((double)Tau_spk[s]);
    val = tt * exp(-tt) * exp((double)W_spk[s]);
  } else {
    double raw = 4.0 * log(xd + 1.0);
    double acc = 0.0;
    for (int i = 0; i < 16; ++i) {
      double phi = (M_PI / 2.0) * (double)i;
      double b = (raw < phi - M_PI || raw > phi + M_PI) ? 0.0
                                                        : (0.5 * cos(raw - phi) + 0.5);
      acc += (double)W_hist[s * 16 + i] * b;
    }
    val = acc;
  }
  filt_out[id] = (float)val;
}

// ---------------- Kernel B: syn = S @ C^T, C staged in LDS tiles ----------------
#define ETILE 500
__global__ __launch_bounds__(256) void synmm_k(const float* __restrict__ S,
                                               const float* __restrict__ C,
                                               float* __restrict__ out, int E) {
  __shared__ __align__(16) float Cs[16][ETILE];
  int tid = threadIdx.x;
  int s = tid & 15, tt = tid >> 4;
  long t = (long)blockIdx.x * 16 + tt;
  const float* Srow = S + t * E;
  float acc = 0.f;
  for (int tb = 0; tb < E; tb += ETILE) {
    __syncthreads();
    for (int i = tid; i < 16 * ETILE; i += 256) {
      int s2 = i / ETILE, k2 = i - s2 * ETILE;
      Cs[s2][k2] = C[(long)s2 * E + tb + k2];
    }
    __syncthreads();
    const float* Crow = &Cs[s][0];
    const float* Sp = Srow + tb;
#pragma unroll 2
    for (int e = 0; e < ETILE; e += 4) {
      float4 a = *(const float4*)(Sp + e);
      float4 c = *(const float4*)(Crow + e);
      acc = fmaf(a.x, c.x, acc); acc = fmaf(a.y, c.y, acc);
      acc = fmaf(a.z, c.z, acc); acc = fmaf(a.w, c.w, acc);
    }
  }
  out[t * 16 + s] = acc;
}

// ---------------- Kernel C: causal depthwise conv + Theta, [t][s] layout ----------------
__global__ void conv_k(const float* __restrict__ syn_e, const float* __restrict__ syn_i,
                       const float* __restrict__ filt, const float* __restrict__ Theta,
                       float* __restrict__ synTh) {
  __shared__ float ek[16][201];
  __shared__ float ik[16][201];
  int tid = threadIdx.x;
  for (int idx = tid; idx < 16 * TNO; idx += 256) {
    ek[idx / TNO][idx % TNO] = filt[idx];
    ik[idx / TNO][idx % TNO] = filt[16 * TNO + idx];
  }
  __syncthreads();
  int s = tid & 15, tt = tid >> 4;
  int t = blockIdx.x * 16 + tt;
  float acc = Theta[s];
  if (t >= TNO) {
#pragma unroll 4
    for (int j = 0; j < TNO; ++j) {
      int u = t - 1 - j;
      acc += ek[s][j] * syn_e[u * 16 + s] + ik[s][j] * syn_i[u * 16 + s];
    }
  } else {
    for (int j = 0; j < t; ++j) {
      int u = t - 1 - j;
      acc += ek[s][j] * syn_e[u * 16 + s] + ik[s][j] * syn_i[u * 16 + s];
    }
  }
  synTh[t * 16 + s] = acc;
}

// ---------------- Kernel D: 9-wave pipeline, minimal-instruction scan wave ----------------
// Delay coverage per step K (hidx = delay-1): chain d=1; pend d<=3 in-group; carry (end
// of iter, from S) hidx 1..6; carry2 (from prev group P) hidx K+4..K+7; near wave (lag-2)
// hidx K+8..K+11; far waves (lag-3) hidx K+12..199. Scan reads 3 b128/iter, no global.
// Wave map: 0=scan, 1=near+reduce, 2=io (spk batch-8, synStage batch-4), 3..8=far.
__global__ __launch_bounds__(576, 1) void scan8_k(const float* __restrict__ synTh,
                                                  const float* __restrict__ filt,
                                                  const float* __restrict__ C_den,
                                                  const float* __restrict__ Tau_spk,
                                                  const float* __restrict__ W_spk,
                                                  float* __restrict__ spk_out) {
  __shared__ __align__(16) float ring[16][452];       // [s][pos], mirror pos+256 for pos<192
  __shared__ __align__(16) float oPartR[3][6][16][4]; // [slot][farwave][s][K]
  __shared__ __align__(16) float farTot[2][16][4];
  __shared__ __align__(16) float nearBuf[2][16][4];
  __shared__ __align__(16) float synStage[2][4][16][20]; // [buf][g&3][s][K(+pad)]
  const int tid = threadIdx.x;
  const int widx = tid >> 6;
  const int l = tid & 63;
  const int s = l & 15, q = l >> 4;

  for (int i = tid; i < 16 * 452; i += 576) (&ring[0][0])[i] = 0.f;
  for (int i = tid; i < 3 * 6 * 16 * 4; i += 576) (&oPartR[0][0][0][0])[i] = 0.f;
  for (int i = tid; i < 2 * 16 * 4; i += 576) {
    (&farTot[0][0][0])[i] = 0.f;
    (&nearBuf[0][0][0])[i] = 0.f;
  }
  __syncthreads();
  if (widx == 2) {  // io: preload synTh groups 0..7
#pragma unroll
    for (int b2 = 0; b2 < 2; ++b2) {
      int e0 = b2 * 256 + 4 * l;
      float4 v = *(const float4*)&synTh[e0];
      int t0 = e0 >> 4, s0 = e0 & 15;
      int g = t0 >> 2, K = t0 & 3;
      synStage[(g >> 2) & 1][g & 3][s0 + 0][K] = v.x;
      synStage[(g >> 2) & 1][g & 3][s0 + 1][K] = v.y;
      synStage[(g >> 2) & 1][g & 3][s0 + 2][K] = v.z;
      synStage[(g >> 2) & 1][g & 3][s0 + 3][K] = v.w;
    }
  }
  __syncthreads();

  if (widx == 0) {
    // ================= scan wave =================
    const float* hrow = filt + (48 + s) * TNO;
    float hk[11];
#pragma unroll
    for (int i = 0; i < 11; ++i) hk[i] = hrow[i];

    float t0v = Tau_spk[0], w0v = W_spk[0];
    bool okrow = (Tau_spk[s] == t0v) && (W_spk[s] == w0v);
    unsigned cd = 0u;
#pragma unroll
    for (int j = 0; j < 16; ++j) {
      float cv = C_den[s * 16 + j];
      okrow = okrow && (cv == 0.f || cv == 1.f);
      cd |= (cv != 0.f) ? (1u << j) : 0u;
    }
    const bool uni = (bool)__all((int)okrow);

    const double tau  = exp((double)Tau_spk[s]);
    const double aa   = exp(-1.0 / tau);
    const double c2a  = exp((double)W_spk[s]) * aa / tau;  // K[d]=C(d-1)a^(d-1), C=w/tau
    const double twoa = 2.0 * aa;
    const double na2  = -aa * aa;

    double twoa4[4], na24[4], c2a4[4], yd0a[4], yd1a[4];
    float cden4[4];
#pragma unroll
    for (int r = 0; r < 4; ++r) {
      int j = 4 * q + r;
      double tj = exp((double)Tau_spk[j]);
      double aj = exp(-1.0 / tj);
      twoa4[r] = 2.0 * aj; na24[r] = -aj * aj;
      c2a4[r]  = exp((double)W_spk[j]) * aj / tj;
      yd0a[r] = 0.0; yd1a[r] = 0.0;
      cden4[r] = C_den[s * 16 + j];
    }

    double zA = 0.0, zB = 0.0;
    float mixu = 0.f, mix1 = 0.f;
    float P0 = 0.f, P1 = 0.f, P2 = 0.f, P3 = 0.f;   // prev group's spikes
    float sgPrev = 0.f;

    // group 0 base: only syn (all gather/carry contributions are t<0 -> 0)
    float4 syn0 = *(const float4*)&synStage[0][0][s][0];
    float oc0 = syn0.x, oc1 = syn0.y, oc2 = syn0.z, oc3 = syn0.w;

#define STEP(SGD, PRE, SGOUT)                                                 \
    {                                                                         \
      float sub = fmaf(hk[0], (SGD), (PRE));                                  \
      unsigned long long bal = __ballot(sub > 0.f);                           \
      float sg = sub > 0.f ? 1.f : 0.f;                                       \
      unsigned mk = (unsigned)bal & 0xFFFFu;                                  \
      if (uni) {                                                              \
        double zc = fma(twoa, zB, fma(na2, zA, c2a * (double)__popc(mk & cd))); \
        zA = zB; zB = zc;                                                     \
        mixu = (float)zA;                                                     \
      } else {                                                                \
        float p = 0.f;                                                        \
        _Pragma("unroll")                                                     \
        for (int r = 0; r < 4; ++r) {                                         \
          double xr = (double)((mk >> (4 * q + r)) & 1u);                     \
          double y2 = fma(twoa4[r], yd1a[r], fma(na24[r], yd0a[r], c2a4[r] * xr)); \
          yd0a[r] = yd1a[r]; yd1a[r] = y2;                                    \
          p = fmaf(cden4[r], (float)y2, p);                                   \
        }                                                                     \
        p += __shfl_xor(p, 16); p += __shfl_xor(p, 32);                       \
        float mixn = mix1; mix1 = p;                                          \
        mixu = mixn;                                                          \
      }                                                                       \
      (SGOUT) = sg;                                                           \
    }

    for (int n = 0; n < NGRP; ++n) {
      // prefetch for group n+1 (producers wrote these at iter n-1; no same-iter races)
      const int gn = n + 1;
      float4 farT  = *(const float4*)&farTot[gn & 1][s][0];
      float4 nearT = *(const float4*)&nearBuf[gn & 1][s][0];
      float4 synT  = *(const float4*)&synStage[(gn >> 2) & 1][gn & 3][s][0];

      float S0, S1, S2, S3;
      STEP(sgPrev, oc0 + mixu, S0)
      float pend2 = hk[1] * S0;
      float pend3 = hk[2] * S0;
      STEP(S0, oc1 + mixu, S1)
      pend3 = fmaf(hk[1], S1, pend3);
      STEP(S1, (oc2 + mixu) + pend2, S2)
      STEP(S2, (oc3 + mixu) + pend3, S3)

      // ring write (spikes t = 4n..4n+3)
      if (l < 16) {
        int u = (4 * n) & 255;
        float4 w0; w0.x = S0; w0.y = S1; w0.z = S2; w0.w = S3;
        *(float4*)&ring[s][u] = w0;
        if (u < 192) *(float4*)&ring[s][u + 256] = w0;
      }

      // carry (from S = group n) hidx 1..6; carry2 (from P = group n-1) hidx K+4..K+7
      float c0 = fmaf(hk[1], S2, fmaf(hk[2], S1, hk[3] * S0));
      float c1 = fmaf(hk[1], S3, fmaf(hk[2], S2, fmaf(hk[3], S1, hk[4] * S0)));
      float c2 = fmaf(hk[2], S3, fmaf(hk[3], S2, fmaf(hk[4], S1, hk[5] * S0)));
      float c3 = fmaf(hk[3], S3, fmaf(hk[4], S2, fmaf(hk[5], S1, hk[6] * S0)));
      float cc0 = fmaf(hk[7], P0, fmaf(hk[6], P1, fmaf(hk[5], P2, hk[4] * P3)));
      float cc1 = fmaf(hk[8], P0, fmaf(hk[7], P1, fmaf(hk[6], P2, hk[5] * P3)));
      float cc2 = fmaf(hk[9], P0, fmaf(hk[8], P1, fmaf(hk[7], P2, hk[6] * P3)));
      float cc3 = fmaf(hk[10], P0, fmaf(hk[9], P1, fmaf(hk[8], P2, hk[7] * P3)));

      oc0 = ((farT.x + nearT.x) + (synT.x + c0)) + cc0;
      oc1 = ((farT.y + nearT.y) + (synT.y + c1)) + cc1;
      oc2 = ((farT.z + nearT.z) + (synT.z + c2)) + cc2;
      oc3 = ((farT.w + nearT.w) + (synT.w + c3)) + cc3;

      P0 = S0; P1 = S1; P2 = S2; P3 = S3;
      sgPrev = S3;
      __syncthreads();
    }
#undef STEP
  } else if (widx == 1) {
    // ================= near + reduce wave =================
    const float* hrow = filt + (48 + s) * TNO;
    float hk[15];
#pragma unroll
    for (int i = 0; i < 15; ++i) hk[i] = hrow[i];

    for (int n = 0; n < NGRP; ++n) {
      int We = (4 * n - 1) & 255;
      if (We < 191) We += 256;
      // near for group n+2: v[j] = spike(4n-4+j), hidx = K+11-j
      float4 v = *(const float4*)&ring[s][We - 3];
      float nr0 = fmaf(hk[11], v.x, fmaf(hk[10], v.y, fmaf(hk[9],  v.z, hk[8]  * v.w)));
      float nr1 = fmaf(hk[12], v.x, fmaf(hk[11], v.y, fmaf(hk[10], v.z, hk[9]  * v.w)));
      float nr2 = fmaf(hk[13], v.x, fmaf(hk[12], v.y, fmaf(hk[11], v.z, hk[10] * v.w)));
      float nr3 = fmaf(hk[14], v.x, fmaf(hk[13], v.y, fmaf(hk[12], v.z, hk[11] * v.w)));
      if (l < 16) {
        float4 nv; nv.x = nr0; nv.y = nr1; nv.z = nr2; nv.w = nr3;
        *(float4*)&nearBuf[(n + 2) & 1][s][0] = nv;
      }
      // reduce far partials for group n+2 (slot (n+2)%3, written by far at n-1)
      const int slot = (n + 2) % 3;
      float4 a0 = *(const float4*)&oPartR[slot][0][s][0];
      float4 a1 = *(const float4*)&oPartR[slot][1][s][0];
      float4 a2 = *(const float4*)&oPartR[slot][2][s][0];
      float4 a3 = *(const float4*)&oPartR[slot][3][s][0];
      float4 a4 = *(const float4*)&oPartR[slot][4][s][0];
      float4 a5 = *(const float4*)&oPartR[slot][5][s][0];
      float4 acc;
      acc.x = ((a0.x + a1.x) + (a2.x + a3.x)) + (a4.x + a5.x);
      acc.y = ((a0.y + a1.y) + (a2.y + a3.y)) + (a4.y + a5.y);
      acc.z = ((a0.z + a1.z) + (a2.z + a3.z)) + (a4.z + a5.z);
      acc.w = ((a0.w + a1.w) + (a2.w + a3.w)) + (a4.w + a5.w);
      if (l < 16) *(float4*)&farTot[(n + 2) & 1][s][0] = acc;
      __syncthreads();
    }
  } else if (widx == 2) {
    // ================= io wave: spk_out (batch 8), synStage (batch 4) =================
    for (int n = 0; n < NGRP; ++n) {
      if ((n & 3) == 2) {
        int g0 = n + 2;                       // g0 % 4 == 0
        if (g0 < NGRP) {
          int e0 = g0 * 64 + 4 * l;
          float4 v = *(const float4*)&synTh[e0];
          int t0 = e0 >> 4, s0 = e0 & 15;
          int g = t0 >> 2, K = t0 & 3;
          int buf = (g >> 2) & 1;
          synStage[buf][g & 3][s0 + 0][K] = v.x;
          synStage[buf][g & 3][s0 + 1][K] = v.y;
          synStage[buf][g & 3][s0 + 2][K] = v.z;
          synStage[buf][g & 3][s0 + 3][K] = v.w;
        }
      }
      if ((n & 7) == 0 && n > 0) {
        int We = (4 * n - 1) & 255;
        if (We < 191) We += 256;
        int base = We - 31;                   // times 4n-32..4n-1
#pragma unroll
        for (int r = 0; r < 2; ++r) {
          int e = 64 * (n - 8) + 256 * r + 4 * l;
          int t0 = e >> 4, s0 = e & 15;
          int pos = base + (t0 - 4 * (n - 8));
          float4 w;
          w.x = ring[s0 + 0][pos]; w.y = ring[s0 + 1][pos];
          w.z = ring[s0 + 2][pos]; w.w = ring[s0 + 3][pos];
          *(float4*)&spk_out[e] = w;
        }
      }
      __syncthreads();
    }
    {   // tail: groups NGRP-8..NGRP-1
      int n = NGRP;
      int We = (4 * n - 1) & 255;
      if (We < 191) We += 256;
      int base = We - 31;
#pragma unroll
      for (int r = 0; r < 2; ++r) {
        int e = 64 * (n - 8) + 256 * r + 4 * l;
        int t0 = e >> 4, s0 = e & 15;
        int pos = base + (t0 - 4 * (n - 8));
        float4 w;
        w.x = ring[s0 + 0][pos]; w.y = ring[s0 + 1][pos];
        w.z = ring[s0 + 2][pos]; w.w = ring[s0 + 3][pos];
        *(float4*)&spk_out[e] = w;
      }
    }
  } else {
    // ================= far waves f=0..5: group n+3, hidx >= K+12 =================
    const int f = widx - 3;
    const int b = 4 * f + q;                 // chunk 0..23, window offsets 8b..8b+7
    const float* hrow = filt + (48 + s) * TNO;
    float ca[11];
#pragma unroll
    for (int m = 0; m < 11; ++m) {
      int hidx = 196 - 8 * b + m;
      ca[m] = (hidx <= 199) ? hrow[hidx] : 0.f;
    }
    v2f pr[11];
    pr[0].x = 0.f; pr[0].y = 0.f;
#pragma unroll
    for (int m = 1; m < 11; ++m) { pr[m].x = ca[m]; pr[m].y = ca[m - 1]; }

    for (int n = 0; n < NGRP; ++n) {
      int We = (4 * n - 1) & 255;
      if (We < 191) We += 256;
      const int Ws = We - 191;
      const float4* rp = (const float4*)&ring[s][Ws + 8 * b];
      float4 V0 = rp[0], V1 = rp[1];
      v2f p01, p23, p45, p67;
      p01.x = V0.x; p01.y = V0.y; p23.x = V0.z; p23.y = V0.w;
      p45.x = V1.x; p45.y = V1.y; p67.x = V1.z; p67.y = V1.w;
      float o[4];
#pragma unroll
      for (int K = 0; K < 4; ++K) {
        v2f a = pr[7 + K] * p01;
        a += pr[5 + K] * p23;
        a += pr[3 + K] * p45;
        a += pr[1 + K] * p67;
        float vv = a.x + a.y;
        vv += __shfl_xor(vv, 16);
        vv += __shfl_xor(vv, 32);
        o[K] = vv;
      }
      if (l < 16) {
        float4 ov; ov.x = o[0]; ov.y = o[1]; ov.z = o[2]; ov.w = o[3];
        *(float4*)&oPartR[n % 3][f][s][0] = ov;
      }
      __syncthreads();
    }
  }
}

extern "C" void kernel_launch(void* const* d_in, const int* in_sizes, int n_in,
                              void* d_out, int out_size, void* d_ws, size_t ws_size,
                              hipStream_t stream) {
  const float* S_e     = (const float*)d_in[0];
  const float* S_i     = (const float*)d_in[1];
  const float* C_den   = (const float*)d_in[2];
  const float* C_syn_e = (const float*)d_in[3];
  const float* C_syn_i = (const float*)d_in[4];
  const float* Tau_e   = (const float*)d_in[5];
  const float* Tau_i   = (const float*)d_in[6];
  const float* W_e     = (const float*)d_in[7];
  const float* W_i     = (const float*)d_in[8];
  const float* D_e     = (const float*)d_in[9];
  const float* D_i     = (const float*)d_in[10];
  const float* Tau_spk = (const float*)d_in[11];
  const float* W_spk   = (const float*)d_in[12];
  const float* W_hist  = (const float*)d_in[13];
  const float* Theta   = (const float*)d_in[14];

  float* out     = (float*)d_out;
  float* spk_out = out;            // 20000*16
  float* filt    = out + 320000;   // 64*200

  float* ws    = (float*)d_ws;
  float* syn_e = ws;               // 320000
  float* syn_i = ws + 320000;      // 320000
  float* synTh = ws + 640000;      // 320000  ([t][s] layout)

  filters_k<<<50, 256, 0, stream>>>(Tau_e, Tau_i, W_e, W_i, D_e, D_i,
                                    Tau_spk, W_spk, W_hist, filt);
  synmm_k<<<1250, 256, 0, stream>>>(S_e, C_syn_e, syn_e, E_NO_C);
  synmm_k<<<1250, 256, 0, stream>>>(S_i, C_syn_i, syn_i, I_NO_C);
  conv_k<<<1250, 256, 0, stream>>>(syn_e, syn_i, filt, Theta, synTh);
  scan8_k<<<1, 576, 0, stream>>>(synTh, filt, C_den, Tau_spk, W_spk, spk_out);
}